// Round 12
// baseline (123.302 us; speedup 1.0000x reference)
//
#include <hip/hip_runtime.h>
#include <cmath>

#define D 128
#define BM 128   // A rows per block tile (held in registers)
#define BN 64    // B cols per staged half-tile (LDS)
#define NSEG 12  // segments per strip-pair -> 64*12 = 768 blocks = 3/CU exactly
#define LOG2E 1.4426950408889634

typedef __attribute__((ext_vector_type(8))) _Float16 f16x8;
typedef __attribute__((ext_vector_type(4))) float f32x4;
typedef __attribute__((ext_vector_type(2))) float f32x2;

// async global->LDS 16B copy; LDS dst wave-uniform base + lane*16, swizzle
// lives in gsrc. R9/R10: builtin immediate ALWAYS 0; fold offsets into ptr.
__device__ __forceinline__ void async_cp16(const void* g, void* l) {
    __builtin_amdgcn_global_load_lds(
        (__attribute__((address_space(1))) void*)g,
        (__attribute__((address_space(3))) void*)l, 16, 0, 0);
}

// ---------------------------------------------------------------------------
// Prep: fp32 x -> fp16 (RTN) combined [x1; x2], per-row El[r] =
// -gamma*log2e*|row|^2 (log2-domain), AND zero the 64 acc slots (block 0).
// ---------------------------------------------------------------------------
__global__ __launch_bounds__(256) void prep_kernel(
    const float* __restrict__ x1, const float* __restrict__ x2,
    _Float16* __restrict__ xh, float* __restrict__ El,
    double* __restrict__ acc, float gl, int N) {
    int tid = threadIdx.x;
    if (blockIdx.x == 0 && tid < 64) acc[tid] = 0.0;
    int r = blockIdx.x * 16 + (tid >> 4);
    if (r >= 2 * N) return;
    int l = tid & 15;
    const float* row = (r < N) ? x1 + (size_t)r * D : x2 + (size_t)(r - N) * D;
    float4 v0 = ((const float4*)row)[l * 2];
    float4 v1 = ((const float4*)row)[l * 2 + 1];
    float v[8] = {v0.x, v0.y, v0.z, v0.w, v1.x, v1.y, v1.z, v1.w};
    float p = 0.f;
    _Float16 h8[8];
#pragma unroll
    for (int j = 0; j < 8; ++j) {
        p = fmaf(v[j], v[j], p);
        h8[j] = (_Float16)v[j];   // RTN-even
    }
    *(uint4*)(xh + (size_t)r * D + l * 8) = *(uint4*)h8;
#pragma unroll
    for (int off = 8; off; off >>= 1) p += __shfl_down(p, off, 16);
    if (l == 0) El[r] = gl * p;   // gl = -gamma*log2e
}

// ---------------------------------------------------------------------------
// R21 probe (resubmit R22 -- round 11 bench was GPUAcquisitionTimeout, no
// data): prep body x32 -> surfaces prep's true duration in the top-5
// (prep = T/32). Writes are idempotent to the real xh/El (same values);
// acc-zeroing goes to a scratch slot. Runs AFTER finalize -> real path
// untouched. Per-rep memory clobber stops CSE/dead-store collapse of reps.
// ---------------------------------------------------------------------------
__global__ __launch_bounds__(256) void prep_probe_kernel(
    const float* __restrict__ x1, const float* __restrict__ x2,
    _Float16* __restrict__ xh, float* __restrict__ El,
    double* __restrict__ accScratch, float gl, int N) {
#pragma unroll 1
    for (int rp = 0; rp < 32; ++rp) {
        int tid = threadIdx.x;
        if (blockIdx.x == 0 && tid < 64) accScratch[tid] = 0.0;
        int r = blockIdx.x * 16 + (tid >> 4);
        if (r < 2 * N) {
            int l = tid & 15;
            const float* row =
                (r < N) ? x1 + (size_t)r * D : x2 + (size_t)(r - N) * D;
            float4 v0 = ((const float4*)row)[l * 2];
            float4 v1 = ((const float4*)row)[l * 2 + 1];
            float v[8] = {v0.x, v0.y, v0.z, v0.w, v1.x, v1.y, v1.z, v1.w};
            float p = 0.f;
            _Float16 h8[8];
#pragma unroll
            for (int j = 0; j < 8; ++j) {
                p = fmaf(v[j], v[j], p);
                h8[j] = (_Float16)v[j];
            }
            *(uint4*)(xh + (size_t)r * D + l * 8) = *(uint4*)h8;
#pragma unroll
            for (int off = 8; off; off >>= 1) p += __shfl_down(p, off, 16);
            if (l == 0) El[r] = gl * p;
        }
        asm volatile("" ::: "memory");   // keep every rep's loads+stores live
    }
}

// ---------------------------------------------------------------------------
// R21 main: exact R14 revert (best measured: 50.5-50.7us, absmax 0.0).
// Post-mortem chain (full history in session journal):
//   R12/R14/R15/R16/R17/R20: six overlap/occupancy schedules, all <= noise
//     or worse. Same-wave MFMA||epilogue overlap DEAD (R20 null + m253
//     external: 2-state pipelining 0.71-1.00x vs sequential).
//   R18/R19 ablation: t0=50.7 = MFMA ~24 (floor 16.7) + epi 17.4 serial
//     + skeleton 8.5; MODE1(no-epi)=33.3us @ MfmaUtil 48% (= the m97-class
//     2-barrier GEMM ceiling; only the full 8-phase restructure is known
//     to break it, and partial ports HURT per m196).
// This round measures the LAST unmeasured component (prep / e2e overhead
// ~52-54us constant) via prep_probe before deciding R22.
// Tripwires: WRITE_SIZE KB-scale, VGPR ~80, bank conflict ~2.1M (accepted).
// Signed weight: bi==bj: +1; same class off-diag: +2; cross class: -2.
// MFMA: v_mfma_f32_16x16x32_f16 (m89/m91-HW-verified C/D layout:
// col = lane&15, row = quad*4 + reg).
// ---------------------------------------------------------------------------
__global__ __launch_bounds__(256, 3) void mmd_mfma_kernel(
    const _Float16* __restrict__ xh, const float* __restrict__ El,
    double* __restrict__ acc, float c2l, int N) {
    __shared__ float4 smem[2][1024];  // 32 KiB: two 16 KiB B half-buffers

    int tid = threadIdx.x;
    int lane = tid & 63, wave = tid >> 6;      // 4 waves
    int quad = lane >> 4, l16 = lane & 15;
    int wrow = (wave & 1) * 64;                // 2 row-groups of 64
    int wcol = (wave >> 1) * 32;               // 2 col-groups of 32

    int nt2 = 2 * N / BM;        // 128 combined block-rows
    int half = N / BM;           // first `half` are x1
    int p = blockIdx.x / NSEG;   // strip pair: rows p and nt2-1-p
    int s = blockIdx.x % NSEG;
    int tpp = nt2 + 1;           // tiles per pair (129)
    int q = tpp / NSEG, r = tpp % NSEG;
    int t0 = s * q + (s < r ? s : r);
    int nt = q + (s < r ? 1 : 0);    // 10 or 11 tiles
    int H = 2 * nt;                  // half-tiles (BN=64 cols each)

    // staging geometry: 16 KiB / 256 thr / 16 B = 4 slots/thread.
    // row = slot>>4 (64 rows x 16 granules), granule XOR-swizzled by row&7.
    int goff[4];
#pragma unroll
    for (int i = 0; i < 4; ++i) {
        int slot = i * 256 + tid;
        int row = slot >> 4;
        int g = (slot & 15) ^ (row & 7);
        goff[i] = row * D + g * 8;
    }

    auto stage = [&](int b2Base, int buf) {
        const _Float16* src = xh + (size_t)b2Base * D;
#pragma unroll
        for (int i = 0; i < 4; ++i)
            async_cp16(src + goff[i], &smem[buf][i * 256 + tid]);
    };
    auto BI = [&](int tt) { return tt <= p ? p : nt2 - 1 - p; };
    auto BJ = [&](int tt) { return tt <= p ? tt : tt - p - 1; };

    // prologue: halves 0 and 1 of tile t0
    stage(BJ(t0) * BM, 0);
    stage(BJ(t0) * BM + BN, 1);

    f16x8 a[4][4];       // A fragments: rows wrow..+64, full K=128 (64 VGPR)
    float4 ea4[4];       // A-side El (reloaded only on strip-row change)
    int curA = -1;
    double dsum = 0.0;

    for (int ht = 0; ht < H; ++ht) {
        int tt = t0 + (ht >> 1), h = ht & 1;
        int bi = BI(tt), bj = BJ(tt);
        int aBase = bi * BM;
        int bcolBase = bj * BM + h * BN;
        float w = (bi == bj) ? 1.0f : 2.0f;
        if ((bi < half) != (bj < half)) w = -2.0f;
        int cur = ht & 1;

        // counted wait: the 4 newest outstanding loads are stage(ht+1)'s;
        // everything older drains. NEVER vmcnt(0) mid-loop.
        if (ht + 1 < H) {
            asm volatile("s_waitcnt vmcnt(4)" ::: "memory");
        } else {
            asm volatile("s_waitcnt vmcnt(0)" ::: "memory");
        }
        __builtin_amdgcn_s_barrier();
        __builtin_amdgcn_sched_barrier(0);

        // B-side El for THIS half-tile: issue early; L2 latency hides under
        // the MFMA phase.
        int bcol0 = bcolBase + wcol + l16;
        float ebv0 = El[bcol0];
        float ebv1 = El[bcol0 + 16];

        // A reload only when the strip row changes (<= 2x per block).
        if (aBase != curA) {
            curA = aBase;
#pragma unroll
            for (int u = 0; u < 4; ++u) {
                int ar = aBase + wrow + u * 16 + l16;
#pragma unroll
                for (int j = 0; j < 4; ++j) {
                    int g = (j >> 1) * 8 + (j & 1) * 4 + quad;
                    a[u][j] = *(const f16x8*)(xh + (size_t)ar * D + g * 8);
                }
            }
            int arow0 = aBase + wrow + quad * 4;
#pragma unroll
            for (int ti = 0; ti < 4; ++ti)
                ea4[ti] = *(const float4*)&El[arow0 + ti * 16];
        }
        __builtin_amdgcn_sched_barrier(0);  // loads issued before MFMA phase

        f32x4 C[4][2];
#pragma unroll
        for (int ti = 0; ti < 4; ++ti)
#pragma unroll
            for (int tj = 0; tj < 2; ++tj) C[ti][tj] = {0.f, 0.f, 0.f, 0.f};

        __builtin_amdgcn_s_setprio(1);
#pragma unroll
        for (int j = 0; j < 4; ++j) {
            int gb = (j >> 1) * 8 + (j & 1) * 4 + quad;
            f16x8 b[2];
#pragma unroll
            for (int u = 0; u < 2; ++u) {
                int br = wcol + u * 16 + l16;
                b[u] = *(const f16x8*)&smem[cur][br * 16 + (gb ^ (br & 7))];
            }
#pragma unroll
            for (int ti = 0; ti < 4; ++ti)
#pragma unroll
                for (int tj = 0; tj < 2; ++tj)
                    C[ti][tj] = __builtin_amdgcn_mfma_f32_16x16x32_f16(
                        a[ti][j], b[tj], C[ti][tj], 0, 0, 0);
        }
        __builtin_amdgcn_s_setprio(0);

        // epilogue: entry = exp2(c2l*d + ea) * 2^eb; accumulate f64 in regs.
        // C/D layout (m89-verified): col = lane&15, row = quad*4 + reg.
        f32x2 cc = {c2l, c2l};
        float lsum = 0.f;
#pragma unroll
        for (int tj = 0; tj < 2; ++tj) {
            f32x2 p2 = {0.f, 0.f};
#pragma unroll
            for (int ti = 0; ti < 4; ++ti) {
                f32x4 d = C[ti][tj];
                f32x2 a01 = cc * f32x2{d.x, d.y} + f32x2{ea4[ti].x, ea4[ti].y};
                f32x2 a23 = cc * f32x2{d.z, d.w} + f32x2{ea4[ti].z, ea4[ti].w};
                f32x2 e, e2;
                e.x = __builtin_amdgcn_exp2f(a01.x);
                e.y = __builtin_amdgcn_exp2f(a01.y);
                e2.x = __builtin_amdgcn_exp2f(a23.x);
                e2.y = __builtin_amdgcn_exp2f(a23.y);
                p2 += e + e2;
            }
            lsum = fmaf(p2.x + p2.y,
                        __builtin_amdgcn_exp2f(tj ? ebv1 : ebv0), lsum);
        }
        dsum += (double)lsum * (double)w;

        // all waves done reading buf[cur] -> overwrite with half-tile ht+2
        __builtin_amdgcn_sched_barrier(0);
        __builtin_amdgcn_s_barrier();
        __builtin_amdgcn_sched_barrier(0);
        if (ht + 2 < H) {
            int tn = t0 + ((ht + 2) >> 1);     // (ht+2)&1 == h
            stage(BJ(tn) * BM + h * BN, cur);
        }
    }

    // block reduction (once per block; last bottom barrier ordered all LDS
    // frag reads before this reuse of the tile buffer as scratch)
#pragma unroll
    for (int off = 32; off; off >>= 1) dsum += __shfl_down(dsum, off);
    double* red = (double*)&smem[0][0];
    if (lane == 0) red[wave] = dsum;
    __syncthreads();
    if (tid == 0)
        atomicAdd(&acc[blockIdx.x & 63], red[0] + red[1] + red[2] + red[3]);
}

// ---------------------------------------------------------------------------
// Finalize: out = sqrt(max(S/N^2, 0)), S already = S11 + S22 - 2*S12.
// ---------------------------------------------------------------------------
__global__ __launch_bounds__(64) void mmd_finalize_kernel(
    const double* __restrict__ acc, float* __restrict__ out, int N) {
    int l = threadIdx.x;
    double v = acc[l];
#pragma unroll
    for (int off = 32; off; off >>= 1) v += __shfl_down(v, off);
    if (l == 0) {
        double nn = (double)N * (double)N;
        double s = v / nn;
        out[0] = (float)sqrt(s > 0.0 ? s : 0.0);
    }
}

extern "C" void kernel_launch(void* const* d_in, const int* in_sizes, int n_in,
                              void* d_out, int out_size, void* d_ws, size_t ws_size,
                              hipStream_t stream) {
    const float* x1 = (const float*)d_in[0];
    const float* x2 = (const float*)d_in[1];
    int N = in_sizes[0] / D;  // 8192

    // ws layout: [0,512) real acc (64 doubles); [512,1024) probe scratch;
    // El @8192 (2N f32); xh @73728 (2N*128 fp16 = 4 MB). Total ~4.07 MB.
    double* acc = (double*)d_ws;
    float* El = (float*)((char*)d_ws + 8192);
    _Float16* xh = (_Float16*)((char*)d_ws + 73728);

    double lg = lgamma(0.5 * (D + 1)) - lgamma(0.5 * D);
    double gz = 2.0 * exp(lg);
    double gamma = 1.0 / (2.0 * gz * gz);
    float gl = (float)(-gamma * LOG2E);        // El scale
    float c2l = (float)(2.0 * gamma * LOG2E);  // dot scale (log2 domain)

    prep_kernel<<<(2 * N + 15) / 16, 256, 0, stream>>>(x1, x2, xh, El, acc, gl, N);

    int nblocks = 64 * NSEG;   // 64 strip-pairs x 12 segments = 768 = 3/CU
    mmd_mfma_kernel<<<nblocks, 256, 0, stream>>>(xh, El, acc, c2l, N);

    mmd_finalize_kernel<<<1, 64, 0, stream>>>(acc, (float*)d_out, N);

    // probe AFTER the real path: prep x32, idempotent writes, scratch acc.
    prep_probe_kernel<<<(2 * N + 15) / 16, 256, 0, stream>>>(
        x1, x2, xh, El, (double*)((char*)d_ws + 512), gl, N);
}

// Round 13
// 109.494 us; speedup vs baseline: 1.1261x; 1.1261x over previous
//
#include <hip/hip_runtime.h>
#include <cmath>

#define D 128
#define BM 128   // strip tile 128x128; wave owns 64 rows x 64 cols (4x16-col steps)
#define NSEG 12  // segments per strip-pair -> 64*12 = 768 blocks = 3/CU exactly
#define LOG2E 1.4426950408889634

typedef __attribute__((ext_vector_type(8))) _Float16 f16x8;
typedef __attribute__((ext_vector_type(4))) float f32x4;
typedef __attribute__((ext_vector_type(2))) float f32x2;

// async global->LDS 16B copy; LDS dst wave-uniform base + lane*16, swizzle
// lives in gsrc. R9/R10: builtin immediate ALWAYS 0; fold offsets into ptr.
__device__ __forceinline__ void async_cp16(const void* g, void* l) {
    __builtin_amdgcn_global_load_lds(
        (__attribute__((address_space(1))) void*)g,
        (__attribute__((address_space(3))) void*)l, 16, 0, 0);
}

// ---------------------------------------------------------------------------
// Prep: fp32 x -> fp16 (RTN) combined [x1; x2], per-row El[r] =
// -gamma*log2e*|row|^2 (log2-domain), AND zero the 64 acc slots (block 0).
// (R21/R22 probe: prep ~0.5us L2-warm -- NOT a lever. Probe removed.)
// ---------------------------------------------------------------------------
__global__ __launch_bounds__(256) void prep_kernel(
    const float* __restrict__ x1, const float* __restrict__ x2,
    _Float16* __restrict__ xh, float* __restrict__ El,
    double* __restrict__ acc, float gl, int N) {
    int tid = threadIdx.x;
    if (blockIdx.x == 0 && tid < 64) acc[tid] = 0.0;
    int r = blockIdx.x * 16 + (tid >> 4);
    if (r >= 2 * N) return;
    int l = tid & 15;
    const float* row = (r < N) ? x1 + (size_t)r * D : x2 + (size_t)(r - N) * D;
    float4 v0 = ((const float4*)row)[l * 2];
    float4 v1 = ((const float4*)row)[l * 2 + 1];
    float v[8] = {v0.x, v0.y, v0.z, v0.w, v1.x, v1.y, v1.z, v1.w};
    float p = 0.f;
    _Float16 h8[8];
#pragma unroll
    for (int j = 0; j < 8; ++j) {
        p = fmaf(v[j], v[j], p);
        h8[j] = (_Float16)v[j];   // RTN-even
    }
    *(uint4*)(xh + (size_t)r * D + l * 8) = *(uint4*)h8;
#pragma unroll
    for (int off = 8; off; off >>= 1) p += __shfl_down(p, off, 16);
    if (l == 0) El[r] = gl * p;   // gl = -gamma*log2e
}

// ---------------------------------------------------------------------------
// R23: private-per-wave LDS strips -- barrier-free AND LDS-fed.
// Ledger (R18/R19/R21 ablations): main 50.2 = matrix-bound 16.7 + ~33 of
// serial pipe time + barrier/drain stall; prep 0.5us; e2e overhead ~53us
// fixed. Barriers phase-lock waves (R14); dropping LDS too put L2 latency
// on the critical path (R15/R17). Untested quadrant = keep LDS, drop
// sharing:
//   * wave owns 64 rows (A regs) x 64 cols of each tile, split into 4
//     steps of 16 cols. B strip (16 cols x K=128 = 4KB) staged into the
//     wave's PRIVATE 2x4KB LDS double buffer by the wave's own 4 cp16.
//   * NO s_barrier in the loop -- no wave reads another's buffer. Each
//     wave self-syncs with counted vmcnt(4) and free-runs; 3 waves/SIMD
//     phase-skew -> one wave's exp2 epilogue overlaps neighbors' MFMAs
//     (m114), with 12cy LDS reads not 300cy L2 on the operand path.
//   * stage(k+2) issued after step k's ds_reads complete (lgkmcnt(0) +
//     sched_barrier fence, rule 18) -> ~600cy prefetch >> L2 latency.
//   * cost: B staged 2x (row-group waves duplicate cols): 528MB L2-res
//     DMA ~15us aggregate, async, below the 17us matrix bound.
// Pre-registered: main >= 48us -> R24 reverts to R14, declares plateau.
// Tripwires: WRITE_SIZE KB-scale (spill), VGPR 120-160.
// Signed weight: bi==bj: +1; same class off-diag: +2; cross class: -2.
// MFMA: v_mfma_f32_16x16x32_f16 (m89/m91-HW-verified C/D layout:
// col = lane&15, row = quad*4 + reg).
// ---------------------------------------------------------------------------
__global__ __launch_bounds__(256, 3) void mmd_mfma_kernel(
    const _Float16* __restrict__ xh, const float* __restrict__ El,
    double* __restrict__ acc, float c2l, int N) {
    __shared__ float4 smem[4][2][256];  // [wave][buf][slot] = 32 KiB

    int tid = threadIdx.x;
    int lane = tid & 63, wave = tid >> 6;      // 4 waves
    int quad = lane >> 4, l16 = lane & 15;
    int wrow = (wave & 1) * 64;                // A row group (64 rows)
    int wcolG = (wave >> 1) * 64;              // B col group (64 cols)

    int nt2 = 2 * N / BM;        // 128 combined block-rows
    int half = N / BM;           // first `half` are x1
    int p = blockIdx.x / NSEG;   // strip pair: rows p and nt2-1-p
    int s = blockIdx.x % NSEG;
    int tpp = nt2 + 1;           // tiles per pair (129)
    int q = tpp / NSEG, r = tpp % NSEG;
    int t0 = s * q + (s < r ? s : r);
    int nt = q + (s < r ? 1 : 0);    // 10 or 11 tiles
    int S = 4 * nt;                  // 16-col steps per wave

    // staging geometry: strip = 16 Gram-cols x K=128 = 4KB; 4 cp16/wave.
    // slot = i*64+lane; row = slot>>4 (strip-local col), granule XOR-swz.
    int goff[4];
#pragma unroll
    for (int i = 0; i < 4; ++i) {
        int slot = i * 64 + lane;
        int rr = slot >> 4;
        int g = (slot & 15) ^ (rr & 7);
        goff[i] = rr * D + g * 8;
    }

    auto stage = [&](int c0, int buf) {
        const _Float16* src = xh + (size_t)c0 * D;
#pragma unroll
        for (int i = 0; i < 4; ++i)
            async_cp16(src + goff[i], &smem[wave][buf][i * 64 + lane]);
    };
    auto BI = [&](int tt) { return tt <= p ? p : nt2 - 1 - p; };
    auto BJ = [&](int tt) { return tt <= p ? tt : tt - p - 1; };
    auto colOf = [&](int k) {
        int tt = t0 + (k >> 2);
        return BJ(tt) * BM + wcolG + (k & 3) * 16;
    };

    // prologue: this wave's steps 0 and 1
    stage(colOf(0), 0);
    stage(colOf(1), 1);

    f16x8 a[4][4];       // A fragments: 64 rows x K=128 (64 VGPR)
    float4 ea4[4];       // A-side El
    int curA = -1;
    double dsum = 0.0;
    f32x2 cc = {c2l, c2l};

    for (int k = 0; k < S; ++k) {
        int tt = t0 + (k >> 2);
        int bi = BI(tt), bj = BJ(tt);
        int aBase = bi * BM;
        float w = (bi == bj) ? 1.0f : 2.0f;
        if ((bi < half) != (bj < half)) w = -2.0f;
        int buf = k & 1;
        int c0 = bj * BM + wcolG + (k & 3) * 16;

        // per-wave counted wait: newest 4 outstanding = stage(k+1); drains
        // stage(k) and everything older. NEVER vmcnt(0) mid-loop.
        if (k + 1 < S) {
            asm volatile("s_waitcnt vmcnt(4)" ::: "memory");
        } else {
            asm volatile("s_waitcnt vmcnt(0)" ::: "memory");
        }
        __builtin_amdgcn_sched_barrier(0);

        // B-side El for this step (L2-hit; hides under MFMA phase)
        float eb = El[c0 + l16];

        // A reload only when the strip row changes (<= 2x per block)
        if (aBase != curA) {
            curA = aBase;
#pragma unroll
            for (int u = 0; u < 4; ++u) {
                int ar = aBase + wrow + u * 16 + l16;
#pragma unroll
                for (int j = 0; j < 4; ++j) {
                    int g = (j >> 1) * 8 + (j & 1) * 4 + quad;
                    a[u][j] = *(const f16x8*)(xh + (size_t)ar * D + g * 8);
                }
            }
            int arow0 = aBase + wrow + quad * 4;
#pragma unroll
            for (int ti = 0; ti < 4; ++ti)
                ea4[ti] = *(const float4*)&El[arow0 + ti * 16];
        }

        // LDS -> register B fragments (private buffer, XOR-swizzled)
        f16x8 b[4];
#pragma unroll
        for (int j = 0; j < 4; ++j) {
            int kc = (j >> 1) * 8 + (j & 1) * 4 + quad;
            b[j] = *(const f16x8*)&smem[wave][buf][l16 * 16 + (kc ^ (l16 & 7))];
        }
        // reads complete -> safe to overwrite this buffer with step k+2.
        // rule 18: inline lgkmcnt needs a sched_barrier fence after it.
        asm volatile("s_waitcnt lgkmcnt(0)" ::: "memory");
        __builtin_amdgcn_sched_barrier(0);
        if (k + 2 < S) stage(colOf(k + 2), buf);
        __builtin_amdgcn_sched_barrier(0);

        f32x4 C[4];
#pragma unroll
        for (int ti = 0; ti < 4; ++ti) C[ti] = {0.f, 0.f, 0.f, 0.f};

        __builtin_amdgcn_s_setprio(1);
#pragma unroll
        for (int j = 0; j < 4; ++j)
#pragma unroll
            for (int ti = 0; ti < 4; ++ti)
                C[ti] = __builtin_amdgcn_mfma_f32_16x16x32_f16(
                    a[ti][j], b[j], C[ti], 0, 0, 0);
        __builtin_amdgcn_s_setprio(0);

        // epilogue: entry = exp2(c2l*d + ea) * 2^eb; f64 accumulate in regs
        f32x2 p2 = {0.f, 0.f};
#pragma unroll
        for (int ti = 0; ti < 4; ++ti) {
            f32x4 d = C[ti];
            f32x2 a01 = cc * f32x2{d.x, d.y} + f32x2{ea4[ti].x, ea4[ti].y};
            f32x2 a23 = cc * f32x2{d.z, d.w} + f32x2{ea4[ti].z, ea4[ti].w};
            f32x2 e, e2;
            e.x = __builtin_amdgcn_exp2f(a01.x);
            e.y = __builtin_amdgcn_exp2f(a01.y);
            e2.x = __builtin_amdgcn_exp2f(a23.x);
            e2.y = __builtin_amdgcn_exp2f(a23.y);
            p2 += e + e2;
        }
        float lsum = (p2.x + p2.y) * __builtin_amdgcn_exp2f(eb);
        dsum += (double)lsum * (double)w;
    }

    // block reduction (the ONLY cross-wave sync; smem reuse is safe only
    // after the first __syncthreads)
#pragma unroll
    for (int off = 32; off; off >>= 1) dsum += __shfl_down(dsum, off);
    __syncthreads();
    double* red = (double*)&smem[0][0][0];
    if (lane == 0) red[wave] = dsum;
    __syncthreads();
    if (tid == 0)
        atomicAdd(&acc[blockIdx.x & 63], red[0] + red[1] + red[2] + red[3]);
}

// ---------------------------------------------------------------------------
// Finalize: out = sqrt(max(S/N^2, 0)), S already = S11 + S22 - 2*S12.
// ---------------------------------------------------------------------------
__global__ __launch_bounds__(64) void mmd_finalize_kernel(
    const double* __restrict__ acc, float* __restrict__ out, int N) {
    int l = threadIdx.x;
    double v = acc[l];
#pragma unroll
    for (int off = 32; off; off >>= 1) v += __shfl_down(v, off);
    if (l == 0) {
        double nn = (double)N * (double)N;
        double s = v / nn;
        out[0] = (float)sqrt(s > 0.0 ? s : 0.0);
    }
}

extern "C" void kernel_launch(void* const* d_in, const int* in_sizes, int n_in,
                              void* d_out, int out_size, void* d_ws, size_t ws_size,
                              hipStream_t stream) {
    const float* x1 = (const float*)d_in[0];
    const float* x2 = (const float*)d_in[1];
    int N = in_sizes[0] / D;  // 8192

    // ws layout: [0,512) acc (64 doubles); El @8192 (2N f32);
    // xh @73728 (2N*128 fp16 = 4 MB). Total ~4.07 MB.
    double* acc = (double*)d_ws;
    float* El = (float*)((char*)d_ws + 8192);
    _Float16* xh = (_Float16*)((char*)d_ws + 73728);

    double lg = lgamma(0.5 * (D + 1)) - lgamma(0.5 * D);
    double gz = 2.0 * exp(lg);
    double gamma = 1.0 / (2.0 * gz * gz);
    float gl = (float)(-gamma * LOG2E);        // El scale
    float c2l = (float)(2.0 * gamma * LOG2E);  // dot scale (log2 domain)

    prep_kernel<<<(2 * N + 15) / 16, 256, 0, stream>>>(x1, x2, xh, El, acc, gl, N);

    int nblocks = 64 * NSEG;   // 64 strip-pairs x 12 segments = 768 = 3/CU
    mmd_mfma_kernel<<<nblocks, 256, 0, stream>>>(xh, El, acc, c2l, N);

    mmd_finalize_kernel<<<1, 64, 0, stream>>>(acc, (float*)d_out, N);
}

// Round 14
// 105.124 us; speedup vs baseline: 1.1729x; 1.0416x over previous
//
#include <hip/hip_runtime.h>
#include <cmath>

#define D 128
#define BM 128   // A rows per block tile (held in registers)
#define BN 64    // B cols per staged half-tile (LDS)
#define NSEG 12  // segments per strip-pair -> 64*12 = 768 blocks = 3/CU exactly
#define LOG2E 1.4426950408889634

typedef __attribute__((ext_vector_type(8))) _Float16 f16x8;
typedef __attribute__((ext_vector_type(4))) float f32x4;
typedef __attribute__((ext_vector_type(2))) float f32x2;

// async global->LDS 16B copy; LDS dst wave-uniform base + lane*16, swizzle
// lives in gsrc. R9/R10: builtin immediate ALWAYS 0; fold offsets into ptr.
__device__ __forceinline__ void async_cp16(const void* g, void* l) {
    __builtin_amdgcn_global_load_lds(
        (__attribute__((address_space(1))) void*)g,
        (__attribute__((address_space(3))) void*)l, 16, 0, 0);
}

// ---------------------------------------------------------------------------
// Prep: fp32 x -> fp16 (RTN) combined [x1; x2], per-row El[r] =
// -gamma*log2e*|row|^2 (log2-domain), AND zero the 64 acc slots (block 0).
// (R21/R22 probe: prep ~0.5us L2-warm -- not a lever.)
// ---------------------------------------------------------------------------
__global__ __launch_bounds__(256) void prep_kernel(
    const float* __restrict__ x1, const float* __restrict__ x2,
    _Float16* __restrict__ xh, float* __restrict__ El,
    double* __restrict__ acc, float gl, int N) {
    int tid = threadIdx.x;
    if (blockIdx.x == 0 && tid < 64) acc[tid] = 0.0;
    int r = blockIdx.x * 16 + (tid >> 4);
    if (r >= 2 * N) return;
    int l = tid & 15;
    const float* row = (r < N) ? x1 + (size_t)r * D : x2 + (size_t)(r - N) * D;
    float4 v0 = ((const float4*)row)[l * 2];
    float4 v1 = ((const float4*)row)[l * 2 + 1];
    float v[8] = {v0.x, v0.y, v0.z, v0.w, v1.x, v1.y, v1.z, v1.w};
    float p = 0.f;
    _Float16 h8[8];
#pragma unroll
    for (int j = 0; j < 8; ++j) {
        p = fmaf(v[j], v[j], p);
        h8[j] = (_Float16)v[j];   // RTN-even
    }
    *(uint4*)(xh + (size_t)r * D + l * 8) = *(uint4*)h8;
#pragma unroll
    for (int off = 8; off; off >>= 1) p += __shfl_down(p, off, 16);
    if (l == 0) El[r] = gl * p;   // gl = -gamma*log2e
}

// ---------------------------------------------------------------------------
// R24: FINAL -- exact R14 revert (best measured: 50.2-50.7us main,
// 105.6-106.8us e2e, absmax 0.0). Pre-registered in R23 ("main >= 48us ->
// revert to R14, declare plateau"); R23 measured 55.0us.
//
// Complete post-mortem ledger (10 experiments, R12-R23):
//   occupancy 2->3->4 waves/SIMD: flat (R12/R14); spill at (512,4) -- gfx950
//     unified VGPR/AGPR file makes that cap 128 TOTAL regs (R13).
//   barrier-free + B-from-L2: -50% (R15/R17; L2 latency on operand path;
//     compiler SINKS reg-prefetch when pressure is high -- VGPR 88 proof).
//   in-wave MFMA||epilogue overlap: spill (R16), null (R20); m253 external
//     microbench concurs (2-state pipelining 0.71-1.00x sequential).
//   barrier-free + private-per-wave LDS: -10% (R23).
//   prep: 0.5us (R21/22 probe); e2e - kernels ~= 53us fixed harness cost.
//   ablation (R18/R19): main 50.2 = matrix-bound 16.7 + serial exp2
//     epilogue 17.4 (irreducible count: one exp2 per Gram element; cannot
//     overlap own MFMAs in-wave) + skeleton 8.5 + MFMA dep-stall ~7.
//     MODE1 (no-epi) = 33.3us @ MfmaUtil 48% = the m97-class 2-barrier
//     GEMM ceiling; only the full 8-phase restructure is known to break
//     that ceiling and partial ports measurably HURT (m196).
// Structural plateau: next levers (full 8-phase port, 32x32 MFMA shape)
// are high-risk / <=3us upside on a 107us e2e dominated by fixed overhead.
// Tripwires (all green here): WRITE_SIZE 24B, VGPR 80, bank conflict 2.1M.
// Signed weight: bi==bj: +1; same class off-diag: +2; cross class: -2.
// MFMA: v_mfma_f32_16x16x32_f16 (m89/m91-HW-verified C/D layout:
// col = lane&15, row = quad*4 + reg).
// ---------------------------------------------------------------------------
__global__ __launch_bounds__(256, 3) void mmd_mfma_kernel(
    const _Float16* __restrict__ xh, const float* __restrict__ El,
    double* __restrict__ acc, float c2l, int N) {
    __shared__ float4 smem[2][1024];  // 32 KiB: two 16 KiB B half-buffers

    int tid = threadIdx.x;
    int lane = tid & 63, wave = tid >> 6;      // 4 waves
    int quad = lane >> 4, l16 = lane & 15;
    int wrow = (wave & 1) * 64;                // 2 row-groups of 64
    int wcol = (wave >> 1) * 32;               // 2 col-groups of 32

    int nt2 = 2 * N / BM;        // 128 combined block-rows
    int half = N / BM;           // first `half` are x1
    int p = blockIdx.x / NSEG;   // strip pair: rows p and nt2-1-p
    int s = blockIdx.x % NSEG;
    int tpp = nt2 + 1;           // tiles per pair (129)
    int q = tpp / NSEG, r = tpp % NSEG;
    int t0 = s * q + (s < r ? s : r);
    int nt = q + (s < r ? 1 : 0);    // 10 or 11 tiles
    int H = 2 * nt;                  // half-tiles (BN=64 cols each)

    // staging geometry: 16 KiB / 256 thr / 16 B = 4 slots/thread.
    // row = slot>>4 (64 rows x 16 granules), granule XOR-swizzled by row&7.
    int goff[4];
#pragma unroll
    for (int i = 0; i < 4; ++i) {
        int slot = i * 256 + tid;
        int row = slot >> 4;
        int g = (slot & 15) ^ (row & 7);
        goff[i] = row * D + g * 8;
    }

    auto stage = [&](int b2Base, int buf) {
        const _Float16* src = xh + (size_t)b2Base * D;
#pragma unroll
        for (int i = 0; i < 4; ++i)
            async_cp16(src + goff[i], &smem[buf][i * 256 + tid]);
    };
    auto BI = [&](int tt) { return tt <= p ? p : nt2 - 1 - p; };
    auto BJ = [&](int tt) { return tt <= p ? tt : tt - p - 1; };

    // prologue: halves 0 and 1 of tile t0
    stage(BJ(t0) * BM, 0);
    stage(BJ(t0) * BM + BN, 1);

    f16x8 a[4][4];       // A fragments: rows wrow..+64, full K=128 (64 VGPR)
    float4 ea4[4];       // A-side El (reloaded only on strip-row change)
    int curA = -1;
    double dsum = 0.0;

    for (int ht = 0; ht < H; ++ht) {
        int tt = t0 + (ht >> 1), h = ht & 1;
        int bi = BI(tt), bj = BJ(tt);
        int aBase = bi * BM;
        int bcolBase = bj * BM + h * BN;
        float w = (bi == bj) ? 1.0f : 2.0f;
        if ((bi < half) != (bj < half)) w = -2.0f;
        int cur = ht & 1;

        // counted wait: the 4 newest outstanding loads are stage(ht+1)'s;
        // everything older drains. NEVER vmcnt(0) mid-loop.
        if (ht + 1 < H) {
            asm volatile("s_waitcnt vmcnt(4)" ::: "memory");
        } else {
            asm volatile("s_waitcnt vmcnt(0)" ::: "memory");
        }
        __builtin_amdgcn_s_barrier();
        __builtin_amdgcn_sched_barrier(0);

        // B-side El for THIS half-tile: issue early; L2 latency hides under
        // the MFMA phase.
        int bcol0 = bcolBase + wcol + l16;
        float ebv0 = El[bcol0];
        float ebv1 = El[bcol0 + 16];

        // A reload only when the strip row changes (<= 2x per block).
        if (aBase != curA) {
            curA = aBase;
#pragma unroll
            for (int u = 0; u < 4; ++u) {
                int ar = aBase + wrow + u * 16 + l16;
#pragma unroll
                for (int j = 0; j < 4; ++j) {
                    int g = (j >> 1) * 8 + (j & 1) * 4 + quad;
                    a[u][j] = *(const f16x8*)(xh + (size_t)ar * D + g * 8);
                }
            }
            int arow0 = aBase + wrow + quad * 4;
#pragma unroll
            for (int ti = 0; ti < 4; ++ti)
                ea4[ti] = *(const float4*)&El[arow0 + ti * 16];
        }
        __builtin_amdgcn_sched_barrier(0);  // loads issued before MFMA phase

        f32x4 C[4][2];
#pragma unroll
        for (int ti = 0; ti < 4; ++ti)
#pragma unroll
            for (int tj = 0; tj < 2; ++tj) C[ti][tj] = {0.f, 0.f, 0.f, 0.f};

        __builtin_amdgcn_s_setprio(1);
#pragma unroll
        for (int j = 0; j < 4; ++j) {
            int gb = (j >> 1) * 8 + (j & 1) * 4 + quad;
            f16x8 b[2];
#pragma unroll
            for (int u = 0; u < 2; ++u) {
                int br = wcol + u * 16 + l16;
                b[u] = *(const f16x8*)&smem[cur][br * 16 + (gb ^ (br & 7))];
            }
#pragma unroll
            for (int ti = 0; ti < 4; ++ti)
#pragma unroll
                for (int tj = 0; tj < 2; ++tj)
                    C[ti][tj] = __builtin_amdgcn_mfma_f32_16x16x32_f16(
                        a[ti][j], b[tj], C[ti][tj], 0, 0, 0);
        }
        __builtin_amdgcn_s_setprio(0);

        // epilogue: entry = exp2(c2l*d + ea) * 2^eb; accumulate f64 in regs.
        // C/D layout (m89-verified): col = lane&15, row = quad*4 + reg.
        f32x2 cc = {c2l, c2l};
        float lsum = 0.f;
#pragma unroll
        for (int tj = 0; tj < 2; ++tj) {
            f32x2 p2 = {0.f, 0.f};
#pragma unroll
            for (int ti = 0; ti < 4; ++ti) {
                f32x4 d = C[ti][tj];
                f32x2 a01 = cc * f32x2{d.x, d.y} + f32x2{ea4[ti].x, ea4[ti].y};
                f32x2 a23 = cc * f32x2{d.z, d.w} + f32x2{ea4[ti].z, ea4[ti].w};
                f32x2 e, e2;
                e.x = __builtin_amdgcn_exp2f(a01.x);
                e.y = __builtin_amdgcn_exp2f(a01.y);
                e2.x = __builtin_amdgcn_exp2f(a23.x);
                e2.y = __builtin_amdgcn_exp2f(a23.y);
                p2 += e + e2;
            }
            lsum = fmaf(p2.x + p2.y,
                        __builtin_amdgcn_exp2f(tj ? ebv1 : ebv0), lsum);
        }
        dsum += (double)lsum * (double)w;

        // all waves done reading buf[cur] -> overwrite with half-tile ht+2
        __builtin_amdgcn_sched_barrier(0);
        __builtin_amdgcn_s_barrier();
        __builtin_amdgcn_sched_barrier(0);
        if (ht + 2 < H) {
            int tn = t0 + ((ht + 2) >> 1);     // (ht+2)&1 == h
            stage(BJ(tn) * BM + h * BN, cur);
        }
    }

    // block reduction (once per block; last bottom barrier ordered all LDS
    // frag reads before this reuse of the tile buffer as scratch)
#pragma unroll
    for (int off = 32; off; off >>= 1) dsum += __shfl_down(dsum, off);
    double* red = (double*)&smem[0][0];
    if (lane == 0) red[wave] = dsum;
    __syncthreads();
    if (tid == 0)
        atomicAdd(&acc[blockIdx.x & 63], red[0] + red[1] + red[2] + red[3]);
}

// ---------------------------------------------------------------------------
// Finalize: out = sqrt(max(S/N^2, 0)), S already = S11 + S22 - 2*S12.
// ---------------------------------------------------------------------------
__global__ __launch_bounds__(64) void mmd_finalize_kernel(
    const double* __restrict__ acc, float* __restrict__ out, int N) {
    int l = threadIdx.x;
    double v = acc[l];
#pragma unroll
    for (int off = 32; off; off >>= 1) v += __shfl_down(v, off);
    if (l == 0) {
        double nn = (double)N * (double)N;
        double s = v / nn;
        out[0] = (float)sqrt(s > 0.0 ? s : 0.0);
    }
}

extern "C" void kernel_launch(void* const* d_in, const int* in_sizes, int n_in,
                              void* d_out, int out_size, void* d_ws, size_t ws_size,
                              hipStream_t stream) {
    const float* x1 = (const float*)d_in[0];
    const float* x2 = (const float*)d_in[1];
    int N = in_sizes[0] / D;  // 8192

    // ws layout: [0,512) acc (64 doubles); El @8192 (2N f32);
    // xh @73728 (2N*128 fp16 = 4 MB). Total ~4.07 MB.
    double* acc = (double*)d_ws;
    float* El = (float*)((char*)d_ws + 8192);
    _Float16* xh = (_Float16*)((char*)d_ws + 73728);

    double lg = lgamma(0.5 * (D + 1)) - lgamma(0.5 * D);
    double gz = 2.0 * exp(lg);
    double gamma = 1.0 / (2.0 * gz * gz);
    float gl = (float)(-gamma * LOG2E);        // El scale
    float c2l = (float)(2.0 * gamma * LOG2E);  // dot scale (log2 domain)

    prep_kernel<<<(2 * N + 15) / 16, 256, 0, stream>>>(x1, x2, xh, El, acc, gl, N);

    int nblocks = 64 * NSEG;   // 64 strip-pairs x 12 segments = 768 = 3/CU
    mmd_mfma_kernel<<<nblocks, 256, 0, stream>>>(xh, El, acc, c2l, N);

    mmd_finalize_kernel<<<1, 64, 0, stream>>>(acc, (float*)d_out, N);
}